// Round 2
// baseline (338.071 us; speedup 1.0000x reference)
//
#include <hip/hip_runtime.h>

// Haar (db1) 2-D DWT, non-overlapping 2x2 block transform.
// Input:  (16, 3, 1024, 1024) fp32
// Output: 4 planes (cA, cH, cV, cD), each (16, 3, 512, 512) fp32, concat flat.
//
// Memory-bound: 192 MiB read + 192 MiB write -> ~64 us floor at 6.3 TB/s.
// R1 change vs R0: fully coalesced loads (lane i -> float4 i, 1 KiB/wave per
// load instruction; R0 had stride-32B lane pattern), and non-temporal stores
// (write-once output, keep it out of L2 so the streaming reads keep the cache).
// Each thread: 2x float4 loads (even/odd input row), 4x 8-byte stores
// (one float2 per output plane) -> 32 B in / 32 B out per thread.

#define IN_W    1024
#define IN_H    1024
#define IMG_IN  (IN_H * IN_W)
#define OUT_W   512
#define OUT_H   512
#define IMG_OUT (OUT_H * OUT_W)
#define N_IMG   48                        // B*C = 16*3
#define PLANE   ((size_t)N_IMG * IMG_OUT) // elements per output plane

typedef float v2f __attribute__((ext_vector_type(2)));

__global__ __launch_bounds__(256) void haar_dwt2_kernel(
    const float* __restrict__ x, float* __restrict__ out)
{
    int t   = blockIdx.x * blockDim.x + threadIdx.x;
    int f   = t & 255;          // float4 index within input row (256 per row)
    int oy  = (t >> 8) & 511;   // output row
    int img = t >> 17;          // (b,c) image index, 0..47

    const float* img_base = x + (size_t)img * IMG_IN;
    // lane i reads float4 i -> wave load is 1 KiB contiguous
    float4 a = ((const float4*)(img_base + (size_t)(2 * oy)     * IN_W))[f]; // even row
    float4 b = ((const float4*)(img_base + (size_t)(2 * oy + 1) * IN_W))[f]; // odd row

    // float4 f covers input cols 4f..4f+3 -> output cols 2f, 2f+1
    v2f cA = { (a.x + a.y + b.x + b.y) * 0.5f, (a.z + a.w + b.z + b.w) * 0.5f };
    v2f cH = { (a.x + a.y - b.x - b.y) * 0.5f, (a.z + a.w - b.z - b.w) * 0.5f };
    v2f cV = { (a.x - a.y + b.x - b.y) * 0.5f, (a.z - a.w + b.z - b.w) * 0.5f };
    v2f cD = { (a.x - a.y - b.x + b.y) * 0.5f, (a.z - a.w - b.z + b.w) * 0.5f };

    size_t o = (size_t)img * IMG_OUT + (size_t)oy * OUT_W + (size_t)(2 * f);
    // streaming stores: write-once data, bypass-friendly (nt policy)
    __builtin_nontemporal_store(cA, (v2f*)(out + 0 * PLANE + o));
    __builtin_nontemporal_store(cH, (v2f*)(out + 1 * PLANE + o));
    __builtin_nontemporal_store(cV, (v2f*)(out + 2 * PLANE + o));
    __builtin_nontemporal_store(cD, (v2f*)(out + 3 * PLANE + o));
}

extern "C" void kernel_launch(void* const* d_in, const int* in_sizes, int n_in,
                              void* d_out, int out_size, void* d_ws, size_t ws_size,
                              hipStream_t stream)
{
    const float* x = (const float*)d_in[0];
    float* out = (float*)d_out;

    // 48 images * 512 output rows * 256 float4-groups = 6,291,456 threads
    int block = 256;
    int grid = (N_IMG * OUT_H * 256) / block;  // 24576
    haar_dwt2_kernel<<<grid, block, 0, stream>>>(x, out);
}